// Round 9
// baseline (724.415 us; speedup 1.0000x reference)
//
#include <hip/hip_runtime.h>

#define NL2E (-1.4426950408889634f)   // -log2(e)
#define NLN2 (-0.6931471805599453f)   // 1/NL2E = -ln(2)
#define K_ITERS 8
#define ZSLOTS 4420                   // zidx(4159)=4418, +pad

__device__ __forceinline__ int zidx(int u) { return u + (u >> 4); }  // bank-skew

__global__ __launch_bounds__(256, 3) void leaf_fp_kernel(
    const float* __restrict__ S_conv, const float* __restrict__ up_mu_Z,
    const float* __restrict__ noise, const float* __restrict__ W_sub,
    const float* __restrict__ theta_syn, const float* __restrict__ theta_spike,
    const float* __restrict__ W_spike, const float* __restrict__ tau_hist,
    const float* __restrict__ K_hist, const float* __restrict__ delta_hist,
    float* __restrict__ out)
{
    const int SUB = 1024;
    int bid = blockIdx.x;
    int s = ((bid & 7) << 7) + (bid >> 3);   // consecutive-s blocks share an XCD/L2
    int x = threadIdx.x;
    int t0 = x << 4;                          // this thread owns t = t0..t0+15
    int ub = 64 + t0;                         // z-buffer index of t0 (64 = history)

    __shared__ float kernLds[64];
    __shared__ float zb[2][ZSLOTS];           // double-buffered z trajectory

    float thsyn = theta_syn[s];
    float thspk = theta_spike[s];
    float wsub  = W_sub[s];
    float wspk  = W_spike[s];
    float delta = delta_hist[s];

    // zero both z buffers (history rows 0..63 stay zero forever = hist0)
    for (int i = x; i < ZSLOTS; i += 256) { zb[0][i] = 0.f; zb[1][i] = 0.f; }

    // taps: c_m (lag m) = NL2E * kern[m-1]; kern[0] == 0 identically (lag 1)
    if (x < 64) {
        float tt = fmaxf((float)x - delta, 0.f);
        float kern = 0.f;
        #pragma unroll
        for (int b = 0; b < 4; ++b) {
            float rtau = __expf(-tau_hist[b]);
            float ttau = tt * rtau;
            kern += ttau * __expf(-ttau) * K_hist[s * 4 + b];
        }
        kernLds[x] = NL2E * kern;
    }

    // per-owned-t inputs, pre-scaled (loop-invariant registers)
    float spreS[16], prezS[16], nraw[16];
    #pragma unroll
    for (int i = 0; i < 16; ++i) {
        size_t off = (size_t)(t0 + i) * SUB + s;
        float sv = S_conv[off];
        float uv = up_mu_Z[off];
        float nv = noise[off];
        spreS[i] = NL2E * (sv + thsyn);
        nraw[i]  = nv;
        prezS[i] = NL2E * (fmaf(0.5f, uv, 0.5f * thspk) + nv);
    }
    float c1 = NL2E * 0.5f * wspk;

    __syncthreads();

    float* Yo = out;
    float* Zo = out + 4194304;
    float* Mo = out + 8388608;
    float* Do = out + 12582912;

    #pragma unroll 1
    for (int k = 0; k < K_ITERS; ++k) {
        const float* zr = zb[k & 1];
        float*       zw_next = zb[(k + 1) & 1];

        // rotating 32-slot register window over z offsets (slot = offset & 31).
        // preload offsets -9..13; loop prefetches 8 taps ahead.
        float zw[32];
        #pragma unroll
        for (int o = -9; o < 14; ++o)
            zw[o & 31] = zr[zidx(ub + o)];

        float acc[16];
        #pragma unroll
        for (int i = 0; i < 16; ++i) acc[i] = 0.f;

        // filtered_t = sum_{m=2}^{64} c_m * z_{t-m}   (register-tiled conv)
        #pragma unroll
        for (int m = 2; m <= 64; ++m) {
            float cm = kernLds[m - 1];
            if (m + 8 <= 64)
                zw[(-(m + 8)) & 31] = zr[zidx(ub - m - 8)];   // prefetch, 8-tap slack
            #pragma unroll
            for (int i = 0; i < 16; ++i)
                acc[i] = fmaf(cm, zw[(i - m) & 31], acc[i]);
        }

        bool last = (k == K_ITERS - 1);
        #pragma unroll
        for (int i = 0; i < 16; ++i) {
            float xin = spreS[i] + acc[i];
            float X = __builtin_amdgcn_rcpf(1.f + __builtin_amdgcn_exp2f(xin));
            float zin = fmaf(c1, X, prezS[i]);
            float z = __builtin_amdgcn_rcpf(1.f + __builtin_amdgcn_exp2f(zin));
            if (!last) {
                zw_next[zidx(ub + i)] = z;
            } else {
                // fused outputs on the final sweep
                size_t o = (size_t)(t0 + i) * SUB + s;
                float down = fmaf(wspk, X, thspk);
                float mu = fmaf(NLN2, zin, -nraw[i]);  // = 0.5*(up+down) exactly
                Yo[o] = X * wsub;
                Zo[o] = z;
                Mo[o] = mu;
                Do[o] = down;
            }
        }
        __syncthreads();
    }
}

extern "C" void kernel_launch(void* const* d_in, const int* in_sizes, int n_in,
                              void* d_out, int out_size, void* d_ws, size_t ws_size,
                              hipStream_t stream) {
    const float* S_conv     = (const float*)d_in[0];
    const float* up_mu_Z    = (const float*)d_in[1];
    const float* noise      = (const float*)d_in[2];
    const float* W_sub      = (const float*)d_in[3];
    const float* theta_syn  = (const float*)d_in[4];
    const float* theta_spike= (const float*)d_in[5];
    const float* W_spike    = (const float*)d_in[6];
    const float* tau_hist   = (const float*)d_in[7];
    const float* K_hist     = (const float*)d_in[8];
    const float* delta_hist = (const float*)d_in[9];
    float* out = (float*)d_out;

    leaf_fp_kernel<<<dim3(1024), dim3(256), 0, stream>>>(
        S_conv, up_mu_Z, noise, W_sub, theta_syn, theta_spike, W_spike,
        tau_hist, K_hist, delta_hist, out);
}

// Round 10
// 211.753 us; speedup vs baseline: 3.4210x; 3.4210x over previous
//
#include <hip/hip_runtime.h>

#define NL2E (-1.4426950408889634f)   // -log2(e)
#define NLN2 (-0.6931471805599453f)   // 1/NL2E = -ln(2)
#define K_ITERS 6
#define ZSLOTS 4420                   // zidx(4159)=4418, +pad

__device__ __forceinline__ int zidx(int u) { return u + (u >> 4); }  // bank-skew

__global__ __launch_bounds__(512, 2) void leaf_fp_kernel(
    const float* __restrict__ S_conv, const float* __restrict__ up_mu_Z,
    const float* __restrict__ noise, const float* __restrict__ W_sub,
    const float* __restrict__ theta_syn, const float* __restrict__ theta_spike,
    const float* __restrict__ W_spike, const float* __restrict__ tau_hist,
    const float* __restrict__ K_hist, const float* __restrict__ delta_hist,
    float* __restrict__ out)
{
    const int SUB = 1024;
    int bid = blockIdx.x;
    int s = ((bid & 7) << 7) + (bid >> 3);   // consecutive-s blocks share an XCD/L2
    int x = threadIdx.x;
    int t0 = x << 3;                          // this thread owns t = t0..t0+7
    int ub = 64 + t0;                         // z-buffer index of t0 (64 = zero history)

    __shared__ float kernLds[64];
    __shared__ float zb[2][ZSLOTS];           // double-buffered z trajectory

    float thsyn = theta_syn[s];
    float thspk = theta_spike[s];
    float wsub  = W_sub[s];
    float wspk  = W_spike[s];
    float delta = delta_hist[s];

    // zero both z buffers (history rows stay zero = hist0)
    {
        float* zz = &zb[0][0];
        for (int i = x; i < 2 * ZSLOTS; i += 512) zz[i] = 0.f;
    }

    // taps: lag m uses kern[m-1]; kern[0] == 0 identically (lag 1 skipped)
    if (x < 64) {
        float tt = fmaxf((float)x - delta, 0.f);
        float kern = 0.f;
        #pragma unroll
        for (int b = 0; b < 4; ++b) {
            float rtau = __expf(-tau_hist[b]);
            float ttau = tt * rtau;
            kern += ttau * __expf(-ttau) * K_hist[s * 4 + b];
        }
        kernLds[x] = NL2E * kern;
    }

    // per-owned-t inputs, pre-scaled (24 loop-invariant registers)
    float spreS[8], prezS[8], nraw[8];
    #pragma unroll
    for (int i = 0; i < 8; ++i) {
        size_t off = (size_t)(t0 + i) * SUB + s;
        float sv = S_conv[off];
        float uv = up_mu_Z[off];
        float nv = noise[off];
        spreS[i] = NL2E * (sv + thsyn);
        nraw[i]  = nv;
        prezS[i] = NL2E * (fmaf(0.5f, uv, 0.5f * thspk) + nv);
    }
    float c1 = NL2E * 0.5f * wspk;

    __syncthreads();

    float* Yo = out;
    float* Zo = out + 4194304;
    float* Mo = out + 8388608;
    float* Do = out + 12582912;

    #pragma unroll 1
    for (int k = 0; k < K_ITERS; ++k) {
        const float* zr = zb[k & 1];
        float*       zwr = zb[(k + 1) & 1];

        // rolling 16-slot register window, slot = (offset d) & 15.
        // preload d in [-9, 5]; loop prefetches with 8-tap slack.
        float zw[16];
        #pragma unroll
        for (int d = -9; d <= 5; ++d)
            zw[d & 15] = zr[zidx(ub + d)];

        float acc[8];
        #pragma unroll
        for (int i = 0; i < 8; ++i) acc[i] = 0.f;

        // filtered_t = sum_{m=2}^{64} c_m * z_{t-m}  (register-tiled conv)
        #pragma unroll
        for (int m = 2; m <= 64; ++m) {
            float cm = kernLds[m - 1];
            if (m <= 56)
                zw[(-(m + 8)) & 15] = zr[zidx(ub - m - 8)];   // prefetch d=-(m+8)
            #pragma unroll
            for (int i = 0; i < 8; ++i)
                acc[i] = fmaf(cm, zw[(i - m) & 15], acc[i]);
        }

        bool last = (k == K_ITERS - 1);
        #pragma unroll
        for (int i = 0; i < 8; ++i) {
            float xin = spreS[i] + acc[i];
            float X = __builtin_amdgcn_rcpf(1.f + __builtin_amdgcn_exp2f(xin));
            float zin = fmaf(c1, X, prezS[i]);
            float z = __builtin_amdgcn_rcpf(1.f + __builtin_amdgcn_exp2f(zin));
            if (!last) {
                zwr[zidx(ub + i)] = z;
            } else {
                // fused outputs on the final sweep
                size_t o = (size_t)(t0 + i) * SUB + s;
                float down = fmaf(wspk, X, thspk);
                float mu = fmaf(NLN2, zin, -nraw[i]);  // = 0.5*(up+down) exactly
                Yo[o] = X * wsub;
                Zo[o] = z;
                Mo[o] = mu;
                Do[o] = down;
            }
        }
        __syncthreads();
    }
}

extern "C" void kernel_launch(void* const* d_in, const int* in_sizes, int n_in,
                              void* d_out, int out_size, void* d_ws, size_t ws_size,
                              hipStream_t stream) {
    const float* S_conv     = (const float*)d_in[0];
    const float* up_mu_Z    = (const float*)d_in[1];
    const float* noise      = (const float*)d_in[2];
    const float* W_sub      = (const float*)d_in[3];
    const float* theta_syn  = (const float*)d_in[4];
    const float* theta_spike= (const float*)d_in[5];
    const float* W_spike    = (const float*)d_in[6];
    const float* tau_hist   = (const float*)d_in[7];
    const float* K_hist     = (const float*)d_in[8];
    const float* delta_hist = (const float*)d_in[9];
    float* out = (float*)d_out;

    leaf_fp_kernel<<<dim3(1024), dim3(512), 0, stream>>>(
        S_conv, up_mu_Z, noise, W_sub, theta_syn, theta_spike, W_spike,
        tau_hist, K_hist, delta_hist, out);
}

// Round 11
// 135.153 us; speedup vs baseline: 5.3599x; 1.5668x over previous
//
#include <hip/hip_runtime.h>

#define NL2E (-1.4426950408889634f)   // -log2(e)
#define KSW 5                         // Gauss-Seidel sweeps (last = output pass)
#define ZP 4176                       // per-unit z row: 64 hist + 4096 + 16 pad

__device__ __forceinline__ float rl(float v, int lane) {
    return __int_as_float(__builtin_amdgcn_readlane(__float_as_int(v), lane));
}

__global__ __launch_bounds__(512, 2) void leaf_gs_kernel(
    const float* __restrict__ S_conv, const float* __restrict__ up_mu_Z,
    const float* __restrict__ noise, const float* __restrict__ W_sub,
    const float* __restrict__ theta_syn, const float* __restrict__ theta_spike,
    const float* __restrict__ W_spike, const float* __restrict__ tau_hist,
    const float* __restrict__ K_hist, const float* __restrict__ delta_hist,
    float* __restrict__ out)
{
    const int SUB = 1024;
    int bid = blockIdx.x;
    // 4 consecutive units per block; 4 line-sharing blocks land on the same XCD
    int s0 = ((bid & 7) << 7) + ((bid >> 3) << 2);
    int x = threadIdx.x;
    int u = x >> 7;            // local unit 0..3 (waves are unit-pure)
    int lix = x & 127;         // lane-in-unit 0..127
    int s = s0 + u;

    __shared__ float zbuf[4][ZP];        // in-place z trajectory (fp32, GS)
    __shared__ float stg[3][512][4];     // Y / Z / down staging for coalesced flush

    float thsyn = theta_syn[s];
    float thspk = theta_spike[s];
    float wsub  = W_sub[s];
    float wspk  = W_spike[s];
    float delta = delta_hist[s];
    float c1 = NL2E * 0.5f * wspk;

    // taps: lane (x&63) computes scaled kern[idx]; broadcast into uniform regs.
    // tap for lag m is kt[m-1]; kt[0] == 0 identically.
    int idxm = x & 63;
    float ttv = fmaxf((float)idxm - delta, 0.f);
    float kern = 0.f;
    #pragma unroll
    for (int b = 0; b < 4; ++b) {
        float rtau = __expf(-tau_hist[b]);
        float ttau = ttv * rtau;
        kern += ttau * __expf(-ttau) * K_hist[s * 4 + b];
    }
    float tapv = NL2E * kern;
    float kt[64];
    #pragma unroll
    for (int m = 0; m < 64; ++m) kt[m] = rl(tapv, m);

    // pre-scaled inputs for the 32 owned timesteps (persist in registers)
    float spre[32], prez[32];
    #pragma unroll
    for (int c = 0; c < 8; ++c) {
        #pragma unroll
        for (int i = 0; i < 4; ++i) {
            int t = (c << 9) + (lix << 2) + i;
            size_t off = (size_t)t * SUB + s;
            float sv = S_conv[off];
            float uv = up_mu_Z[off];
            float nv = noise[off];
            spre[(c << 2) + i] = NL2E * (sv + thsyn);
            prez[(c << 2) + i] = NL2E * (fmaf(0.5f, uv, 0.5f * thspk) + nv);
        }
    }

    // zero z (history [0,64) stays zero = hist0; rest = initial guess 0)
    for (int i = x; i < 4 * ZP; i += 512) (&zbuf[0][0])[i] = 0.f;
    __syncthreads();

    float4* zq = (float4*)&zbuf[u][0];   // quad Q covers t in [4Q-64, 4Q-61]
    float* Yo = out;
    float* Zo = out + 4194304;
    float* Mo = out + 8388608;
    float* Do = out + 12582912;

    #pragma unroll 1
    for (int k = 0; k < KSW; ++k) {
        bool last = (k == KSW - 1);
        #pragma unroll
        for (int c = 0; c < 8; ++c) {
            // thread owns t = T0..T0+3, T0 = c*512 + 4*lix
            int q0 = (c << 7) + lix;     // window quad base: t = T0-64+4j, j=0..16
            float acc[4] = {0.f, 0.f, 0.f, 0.f};
            #pragma unroll
            for (int j = 0; j <= 16; ++j) {
                float4 q = zq[q0 + j];   // stride-1 quads across lanes: conflict-free
                float qe[4] = {q.x, q.y, q.z, q.w};
                #pragma unroll
                for (int i = 0; i < 4; ++i) {
                    #pragma unroll
                    for (int e = 0; e < 4; ++e) {
                        int idx = 63 - 4 * j + i - e;   // tap index = lag-1
                        if (idx >= 0 && idx < 64)
                            acc[i] = fmaf(kt[idx], qe[e], acc[i]);
                    }
                }
            }
            float zn[4], Xv[4];
            #pragma unroll
            for (int i = 0; i < 4; ++i) {
                float xin = spre[(c << 2) + i] + acc[i];
                float X = __builtin_amdgcn_rcpf(1.f + __builtin_amdgcn_exp2f(xin));
                float zin = fmaf(c1, X, prez[(c << 2) + i]);
                zn[i] = __builtin_amdgcn_rcpf(1.f + __builtin_amdgcn_exp2f(zin));
                Xv[i] = X;
            }
            if (!last) {
                __syncthreads();                      // all reads of old section done
                zq[q0 + 16] = make_float4(zn[0], zn[1], zn[2], zn[3]);
                __syncthreads();                      // new values visible downstream
            } else {
                // stage per-unit outputs, then flush coalesced (float4 across units)
                #pragma unroll
                for (int i = 0; i < 4; ++i) {
                    int tl = (lix << 2) + i;
                    stg[0][tl][u] = Xv[i] * wsub;
                    stg[1][tl][u] = zn[i];
                    stg[2][tl][u] = fmaf(wspk, Xv[i], thspk);
                }
                __syncthreads();
                {
                    int tl = x & 511;
                    int t = (c << 9) + tl;
                    size_t go = (size_t)t * SUB + s0;
                    float4 dq  = *(float4*)&stg[2][tl][0];
                    float4 uq  = *(const float4*)&up_mu_Z[go];
                    float4 yq  = *(float4*)&stg[0][tl][0];
                    float4 zq4 = *(float4*)&stg[1][tl][0];
                    float4 mq = make_float4(0.5f * (uq.x + dq.x), 0.5f * (uq.y + dq.y),
                                            0.5f * (uq.z + dq.z), 0.5f * (uq.w + dq.w));
                    *(float4*)&Yo[go] = yq;
                    *(float4*)&Zo[go] = zq4;
                    *(float4*)&Mo[go] = mq;
                    *(float4*)&Do[go] = dq;
                }
                __syncthreads();
            }
        }
    }
}

extern "C" void kernel_launch(void* const* d_in, const int* in_sizes, int n_in,
                              void* d_out, int out_size, void* d_ws, size_t ws_size,
                              hipStream_t stream) {
    const float* S_conv     = (const float*)d_in[0];
    const float* up_mu_Z    = (const float*)d_in[1];
    const float* noise      = (const float*)d_in[2];
    const float* W_sub      = (const float*)d_in[3];
    const float* theta_syn  = (const float*)d_in[4];
    const float* theta_spike= (const float*)d_in[5];
    const float* W_spike    = (const float*)d_in[6];
    const float* tau_hist   = (const float*)d_in[7];
    const float* K_hist     = (const float*)d_in[8];
    const float* delta_hist = (const float*)d_in[9];
    float* out = (float*)d_out;

    leaf_gs_kernel<<<dim3(256), dim3(512), 0, stream>>>(
        S_conv, up_mu_Z, noise, W_sub, theta_syn, theta_spike, W_spike,
        tau_hist, K_hist, delta_hist, out);
}